// Round 4
// baseline (1114.505 us; speedup 1.0000x reference)
//
#include <hip/hip_runtime.h>

typedef _Float16 half8 __attribute__((ext_vector_type(8)));
typedef _Float16 half4v __attribute__((ext_vector_type(4)));
typedef float f32x4v __attribute__((ext_vector_type(4)));

#define Bn 4
#define Hn 128
#define Wn 128
#define HW (Hn*Wn)
#define Cn 17
#define STEPSn 48
#define NPIX (Bn*HW)

// d_ws layout (bytes):
#define W1IMG_OFF 0          // 128 x 72 fp16 (K padded 51->64)
#define W2IMG_OFF 18432      // 32 x 128 fp16 (rows 17..31 zero)

// One-time weight conversion to padded fp16 images.
__global__ __launch_bounds__(256) void nca_prep(
    const float* __restrict__ W1, const float* __restrict__ W2,
    _Float16* __restrict__ w1img, _Float16* __restrict__ w2img)
{
  int t = blockIdx.x * 256 + threadIdx.x;
  if (t < 128 * 72) {
    int r = t / 72, k = t - r * 72;
    w1img[t] = (k < 51) ? (_Float16)W1[r * 51 + k] : (_Float16)0.f;
  } else {
    int u = t - 128 * 72;
    if (u < 32 * 128) {
      int r = u >> 7, k = u & 127;
      w2img[u] = (r < 17) ? (_Float16)W2[r * 128 + k] : (_Float16)0.f;
    }
  }
}

// Fused step kernel: one block = 16x16 interior pixels + 18x18 halo (324 px).
// The MLP is recomputed for halo pixels (bit-identical to neighbor blocks'
// interior computation), so the post-alive maxpool needs no second kernel.
// Reads masked state dev_path[s-1]; writes masked state dev_path[s].
__global__ __launch_bounds__(512, 2) void nca_step(
    const float* __restrict__ state, const float* __restrict__ rplane,
    const _Float16* __restrict__ w1img, const float* __restrict__ b1,
    const _Float16* __restrict__ w2img, const float* __restrict__ b2,
    float* __restrict__ outS)
{
  __shared__ _Float16 p_t[336][72];    // 48384 B   (stride 144B: 16B-aligned)
  __shared__ _Float16 h_t[336][136];   // 91392 B   (stride 272B: 16B-aligned)
  __shared__ float ch3s[18][18];       // pre-alive ch3 (masked old state)
  __shared__ float ch3u[18][18];       // post ch3 (unmasked new)

  const int tid = threadIdx.x;
  const int lane = tid & 63;
  const int w = tid >> 6;        // wave 0..7
  const int l15 = lane & 15;
  const int g = lane >> 4;       // 0..3

  const int bx = blockIdx.x;     // 256 blocks: b(2) | tileY(3) | tileX(3)
  const int b = bx >> 6;
  const int tIdx = bx & 63;
  const int gy0 = ((tIdx >> 3) & 7) << 4;
  const int gx0 = (tIdx & 7) << 4;

  const float* sb = state + (size_t)b * Cn * HW;
  const float* rb = rplane + (size_t)b * HW;
  float* ob = outS + (size_t)b * Cn * HW;

  // ---- Phase 1: sobel + rotation -> p_t (fp16); stash pre-alive ch3 ----
  for (int idx = tid; idx < 648; idx += 512) {
    int px = idx >> 1, hf = idx & 1;          // (pixel, channel-half)
    int ty = (px * 57) >> 10, tx = px - ty * 18;   // exact /18 for px<336
    int gY = gy0 + ty - 1, gX = gx0 + tx - 1;
    bool rm = (unsigned)gY < 128u, cm = (unsigned)gX < 128u;
    bool ru = (unsigned)(gY - 1) < 128u, rd = (unsigned)(gY + 1) < 128u;
    bool cl = (unsigned)(gX - 1) < 128u, cr = (unsigned)(gX + 1) < 128u;
    bool inb = rm && cm;
    float ca = 1.f, sa = 0.f;
    if (inb) { float ang = sb[16 * HW + gY * Wn + gX]; ca = cosf(ang); sa = sinf(ang); }
    int r0 = (gY - 1) * Wn + gX, r1 = gY * Wn + gX, r2 = (gY + 1) * Wn + gX;
    int c0 = hf ? 9 : 0, cEnd = hf ? 17 : 9;
    for (int c = c0; c < cEnd; ++c) {
      const float* sc = sb + c * HW;
      float n00=0,n01=0,n02=0,n10=0,n11=0,n12=0,n20=0,n21=0,n22=0;
      if (ru) { if (cl) n00 = sc[r0-1]; if (cm) n01 = sc[r0]; if (cr) n02 = sc[r0+1]; }
      if (rm) { if (cl) n10 = sc[r1-1]; if (cm) n11 = sc[r1]; if (cr) n12 = sc[r1+1]; }
      if (rd) { if (cl) n20 = sc[r2-1]; if (cm) n21 = sc[r2]; if (cr) n22 = sc[r2+1]; }
      float sx = (n02-n00 + 2.f*(n12-n10) + n22-n20) * 0.125f;
      float sy = (n20-n00 + 2.f*(n21-n01) + n22-n02) * 0.125f;
      p_t[px][c]      = (_Float16)n11;
      p_t[px][17 + c] = (_Float16)(ca * sx + sa * sy);   // px
      p_t[px][34 + c] = (_Float16)(ca * sy - sa * sx);   // py
      if (!hf && c == 3) ch3s[ty][tx] = inb ? n11 : -1e30f;
    }
    if (hf) { for (int k = 57; k < 64; ++k) p_t[px][k] = (_Float16)0.f; }
    else    { for (int k = 51; k < 57; ++k) p_t[px][k] = (_Float16)0.f; }
  }
  __syncthreads();

  // ---- Phase 2: GEMM1  h[128 x 336] = relu(W1 p + b1) -> h_t fp16 ----
  {
    const int hid0 = w * 16 + g * 4;
    const _Float16* w1r = w1img + (w * 16 + l15) * 72;
    half8 a1f0 = *(const half8*)(w1r + g * 8);
    half8 a1f1 = *(const half8*)(w1r + 32 + g * 8);
    f32x4v b1v = *(const f32x4v*)(b1 + hid0);
#pragma unroll
    for (int nt = 0; nt < 21; ++nt) {
      const _Float16* pr = &p_t[nt * 16 + l15][g * 8];
      half8 bf0 = *(const half8*)(pr);
      half8 bf1 = *(const half8*)(pr + 32);
      f32x4v acc = (f32x4v){0.f, 0.f, 0.f, 0.f};
      acc = __builtin_amdgcn_mfma_f32_16x16x32_f16(a1f0, bf0, acc, 0, 0, 0);
      acc = __builtin_amdgcn_mfma_f32_16x16x32_f16(a1f1, bf1, acc, 0, 0, 0);
      half4v hv;
#pragma unroll
      for (int i = 0; i < 4; ++i) hv[i] = (_Float16)fmaxf(acc[i] + b1v[i], 0.f);
      *(half4v*)(&h_t[nt * 16 + l15][hid0]) = hv;
    }
  }
  __syncthreads();

  // ---- Phase 3: GEMM2  dx[32 x 336] = W2 h ; wave w owns nt = {w, w+8, w+16} ----
  const int nnt = (w < 5) ? 3 : 2;
  int ntv[3] = {w, w + 8, w + 16};
  f32x4v acc2[3][2];
#pragma unroll
  for (int j = 0; j < 3; ++j)
#pragma unroll
    for (int m = 0; m < 2; ++m) acc2[j][m] = (f32x4v){0.f, 0.f, 0.f, 0.f};
#pragma unroll
  for (int kc = 0; kc < 4; ++kc) {
    half8 w2a = *(const half8*)(w2img + l15 * 128 + kc * 32 + g * 8);
    half8 w2b = *(const half8*)(w2img + (16 + l15) * 128 + kc * 32 + g * 8);
    for (int j = 0; j < nnt; ++j) {     // nnt wave-uniform
      half8 bf = *(const half8*)(&h_t[ntv[j] * 16 + l15][kc * 32 + g * 8]);
      acc2[j][0] = __builtin_amdgcn_mfma_f32_16x16x32_f16(w2a, bf, acc2[j][0], 0, 0, 0);
      acc2[j][1] = __builtin_amdgcn_mfma_f32_16x16x32_f16(w2b, bf, acc2[j][1], 0, 0, 0);
    }
  }

  // ---- Epilogue: new = state + dx*upd (unmasked); publish ch3u ----
  float newv[3][4], new16[3];
  int typ[3], txp[3];
  bool act[3];
  f32x4v b2v = *(const f32x4v*)(b2 + g * 4);
  float b2_16 = b2[16];
  for (int j = 0; j < nnt; ++j) {
    int px = ntv[j] * 16 + l15;
    int ty = (px * 57) >> 10, tx = px - ty * 18;
    typ[j] = ty; txp[j] = tx;
    bool pxok = px < 324;
    int gY = gy0 + ty - 1, gX = gx0 + tx - 1;
    bool inb = pxok && (unsigned)gY < 128u && (unsigned)gX < 128u;
    act[j] = inb;
    float n3 = -1e30f;
    if (inb) {
      int ip = gY * Wn + gX;
      float upd = (rb[ip] < 0.5f) ? 1.f : 0.f;
#pragma unroll
      for (int i = 0; i < 4; ++i)
        newv[j][i] = fmaf(acc2[j][0][i] + b2v[i], upd, sb[(g * 4 + i) * HW + ip]);
      if (g == 0) {
        n3 = newv[j][3];
        new16[j] = fmaf(acc2[j][1][0] + b2_16, upd, sb[16 * HW + ip]);
      }
    }
    if (g == 0 && pxok) ch3u[ty][tx] = inb ? n3 : -1e30f;
  }
  __syncthreads();

  // ---- Phase 4: alive gate + masked store (interior pixels only) ----
  for (int j = 0; j < nnt; ++j) {
    if (!act[j]) continue;
    int ty = typ[j], tx = txp[j];
    if (ty < 1 || ty > 16 || tx < 1 || tx > 16) continue;
    float pre = -1e30f, post = -1e30f;
#pragma unroll
    for (int dy = -1; dy <= 1; ++dy)
#pragma unroll
      for (int dx = -1; dx <= 1; ++dx) {
        pre = fmaxf(pre, ch3s[ty + dy][tx + dx]);
        post = fmaxf(post, ch3u[ty + dy][tx + dx]);
      }
    float alive = (pre > 0.1f && post > 0.1f) ? 1.f : 0.f;
    int ip = (gy0 + ty - 1) * Wn + (gx0 + tx - 1);
#pragma unroll
    for (int i = 0; i < 4; ++i) ob[(g * 4 + i) * HW + ip] = newv[j][i] * alive;
    if (g == 0) ob[16 * HW + ip] = new16[j] * alive;
  }
}

__global__ __launch_bounds__(256) void nca_final(
    const float* __restrict__ last, float* __restrict__ out4)
{
  int tid = blockIdx.x * blockDim.x + threadIdx.x; // B*4*H*W
  int x = tid & 127, y = (tid >> 7) & 127, c = (tid >> 14) & 3, b = tid >> 16;
  out4[tid] = last[(((size_t)b * Cn + c) * Hn + y) * Wn + x];
}

extern "C" void kernel_launch(void* const* d_in, const int* in_sizes, int n_in,
                              void* d_out, int out_size, void* d_ws, size_t ws_size,
                              hipStream_t stream) {
  const float* init_state = (const float*)d_in[0];
  const float* rand_all   = (const float*)d_in[1];
  const float* W1 = (const float*)d_in[2];
  const float* b1 = (const float*)d_in[3];
  const float* W2 = (const float*)d_in[4];
  const float* b2 = (const float*)d_in[5];

  float* out = (float*)d_out;
  float* final4 = out;                                   // [B,4,H,W]
  float* dev_path = out + (size_t)Bn * 4 * HW;           // [STEPS,B,C,H,W]
  char* ws = (char*)d_ws;
  _Float16* w1img = (_Float16*)(ws + W1IMG_OFF);
  _Float16* w2img = (_Float16*)(ws + W2IMG_OFF);

  const size_t stateSz = (size_t)Bn * Cn * HW;

  hipLaunchKernelGGL(nca_prep, dim3(52), dim3(256), 0, stream, W1, W2, w1img, w2img);

  for (int s = 0; s < STEPSn; ++s) {
    const float* cur = (s == 0) ? init_state
                                : (const float*)(dev_path + (size_t)(s - 1) * stateSz);
    float* nxt = dev_path + (size_t)s * stateSz;
    const float* rp = rand_all + (size_t)s * NPIX;
    hipLaunchKernelGGL(nca_step, dim3(256), dim3(512), 0, stream,
                       cur, rp, w1img, b1, w2img, b2, nxt);
  }
  hipLaunchKernelGGL(nca_final, dim3((size_t)Bn * 4 * HW / 256), dim3(256), 0,
                     stream, dev_path + (size_t)(STEPSn - 1) * stateSz, final4);
}

// Round 5
// 735.775 us; speedup vs baseline: 1.5147x; 1.5147x over previous
//
#include <hip/hip_runtime.h>

typedef _Float16 half8 __attribute__((ext_vector_type(8)));
typedef _Float16 half4v __attribute__((ext_vector_type(4)));
typedef float f32x4v __attribute__((ext_vector_type(4)));

#define Bn 4
#define Hn 128
#define Wn 128
#define HW (Hn*Wn)
#define Cn 17
#define STEPSn 48
#define NPIX (Bn*HW)

// tile geometry: interior 4 rows x 16 cols; M-halo 6x18; alive-plane window 8x20
#define TY 4
#define TX 16
#define MRr 6
#define MCc 18
#define PRr 8
#define PCc 20

// ws layout (bytes)
#define W1IMG_OFF 0          // 128 x 72 fp16
#define W2IMG_OFF 18432      // 32 x 128 fp16
#define ULAST_OFF 32768      // U_47: B*C*H*W f32 = 4456448 B

__global__ __launch_bounds__(256) void nca_prep(
    const float* __restrict__ W1, const float* __restrict__ W2,
    _Float16* __restrict__ w1img, _Float16* __restrict__ w2img)
{
  int t = blockIdx.x * 256 + threadIdx.x;
  if (t < 128 * 72) {
    int r = t / 72, k = t - r * 72;
    w1img[t] = (k < 51) ? (_Float16)W1[r * 51 + k] : (_Float16)0.f;
  } else {
    int u = t - 128 * 72;
    if (u < 32 * 128) {
      int r = u >> 7, k = u & 127;
      w2img[u] = (r < 17) ? (_Float16)W2[r * 128 + k] : (_Float16)0.f;
    }
  }
}

// step_s: reads unmasked U_{s-1} (MODE1) or init_state (MODE0).
// MODE1: reconstructs masked M_{s-1} on the 6x18 halo tile from U_{s-1} and
// the alive gate (maxpool planes of M_{s-2}.ch3 and U_{s-1}.ch3), writes
// M_{s-1} interior to dev_path[s-1] (bit-identical across blocks: same fmax
// order, same inputs). Then sobel+MLP on the masked tile -> U_s interior.
template<int MODE>
__global__ __launch_bounds__(256, 2) void nca_step(
    const float* __restrict__ prevU,      // [B][17][H][W]: U_{s-1} or init_state
    const float* __restrict__ prev2,      // [B][17][H][W]: M_{s-2} (ch3 used); MODE0 unused
    const float* __restrict__ rplane,     // rand + s*B*HW
    const _Float16* __restrict__ w1img, const float* __restrict__ b1,
    const _Float16* __restrict__ w2img, const float* __restrict__ b2,
    float* __restrict__ outU,             // U_s
    float* __restrict__ outM)             // dev_path[s-1]; MODE0 unused
{
  __shared__ float pm[PRr][PCc];          // M_{s-2} ch3 plane window
  __shared__ float pu[PRr][PCc];          // U_{s-1} ch3 plane window
  __shared__ float alv[MRr][MCc];         // alive_{s-1} per M-cell
  __shared__ float Mt[Cn][MRr][MCc];      // masked M_{s-1} tile (+ zeros off-image)
  __shared__ _Float16 pscr[4][16][72];    // per-wave p fragments
  __shared__ _Float16 hscr[4][16][136];   // per-wave h fragments

  const int tid = threadIdx.x;
  const int bx = blockIdx.x;              // 1024: b(2) | tileY(5) | tileX(3)
  const int b = bx >> 8;
  const int tIdx = bx & 255;
  const int y0 = ((tIdx >> 3) & 31) * TY;
  const int x0 = (tIdx & 7) * TX;

  const float* ub = prevU + (size_t)b * Cn * HW;

  // ---- Phase A (MODE1): alive planes + per-cell alive gate ----
  if (MODE) {
    const float* u3 = ub + 3 * HW;
    const float* m3 = prev2 + ((size_t)b * Cn + 3) * HW;
    for (int i = tid; i < PRr * PCc; i += 256) {
      int py = i / PCc, px = i - py * PCc;
      int gY = y0 + py - 2, gX = x0 + px - 2;
      bool in = (unsigned)gY < 128u && (unsigned)gX < 128u;
      pu[py][px] = in ? u3[gY * Wn + gX] : -1e30f;
      pm[py][px] = in ? m3[gY * Wn + gX] : -1e30f;
    }
    __syncthreads();
    if (tid < MRr * MCc) {
      int my = tid / MCc, mx = tid - my * MCc;
      float pre = -1e30f, post = -1e30f;
#pragma unroll
      for (int dy = 0; dy < 3; ++dy)
#pragma unroll
        for (int dxx = 0; dxx < 3; ++dxx) {
          pre  = fmaxf(pre,  pm[my + dy][mx + dxx]);
          post = fmaxf(post, pu[my + dy][mx + dxx]);
        }
      alv[my][mx] = (pre > 0.1f && post > 0.1f) ? 1.f : 0.f;
    }
    __syncthreads();
  }

  // ---- Phase B: build masked tile Mt; write M_{s-1} interior to dev_path ----
  for (int item = tid; item < Cn * MRr * MCc; item += 256) {
    int cg = item / (MRr * MCc);
    int cell = item - cg * (MRr * MCc);
    int my = cell / MCc, mx = cell - my * MCc;
    int gY = y0 + my - 1, gX = x0 + mx - 1;
    bool in = (unsigned)gY < 128u && (unsigned)gX < 128u;
    float v = 0.f;
    if (in) {
      v = ub[cg * HW + gY * Wn + gX];
      if (MODE) v *= alv[my][mx];
    }
    Mt[cg][my][mx] = v;
    if (MODE && in && my >= 1 && my <= TY && mx >= 1 && mx <= TX)
      outM[((size_t)b * Cn + cg) * HW + gY * Wn + gX] = v;
  }
  __syncthreads();

  // ---- Phase C: per-wave sobel + rotation -> pscr (wave w = interior row w) ----
  const int w = tid >> 6, lane = tid & 63, l15 = lane & 15, g = lane >> 4;
  {
    int my = w + 1, mx = l15 + 1;
    float ang = Mt[16][my][mx];
    float ca = cosf(ang), sa = sinf(ang);
#pragma unroll
    for (int j = 0; j < 5; ++j) {
      int c = g + 4 * j;
      if (c >= Cn) break;
      float n00 = Mt[c][my-1][mx-1], n01 = Mt[c][my-1][mx], n02 = Mt[c][my-1][mx+1];
      float n10 = Mt[c][my  ][mx-1], n11 = Mt[c][my  ][mx], n12 = Mt[c][my  ][mx+1];
      float n20 = Mt[c][my+1][mx-1], n21 = Mt[c][my+1][mx], n22 = Mt[c][my+1][mx+1];
      float sx = (n02 - n00 + 2.f * (n12 - n10) + n22 - n20) * 0.125f;
      float sy = (n20 - n00 + 2.f * (n21 - n01) + n22 - n02) * 0.125f;
      pscr[w][l15][c]      = (_Float16)n11;
      pscr[w][l15][17 + c] = (_Float16)(ca * sx + sa * sy);
      pscr[w][l15][34 + c] = (_Float16)(ca * sy - sa * sx);
    }
#pragma unroll
    for (int j = 0; j < 4; ++j) {           // zero K-pad 51..63
      int k = 51 + g + 4 * j;
      if (k > 63) break;
      pscr[w][l15][k] = (_Float16)0.f;
    }
  }
  __syncthreads();

  // ---- Phase D: GEMM1  h = relu(W1 p + b1) -> hscr (wave-local tile) ----
  {
    half8 bf0 = *(const half8*)(&pscr[w][l15][g * 8]);
    half8 bf1 = *(const half8*)(&pscr[w][l15][32 + g * 8]);
#pragma unroll
    for (int m = 0; m < 8; ++m) {
      const _Float16* w1r = w1img + (m * 16 + l15) * 72;
      half8 a0 = *(const half8*)(w1r + g * 8);
      half8 a1f = *(const half8*)(w1r + 32 + g * 8);
      f32x4v acc = (f32x4v){0.f, 0.f, 0.f, 0.f};
      acc = __builtin_amdgcn_mfma_f32_16x16x32_f16(a0, bf0, acc, 0, 0, 0);
      acc = __builtin_amdgcn_mfma_f32_16x16x32_f16(a1f, bf1, acc, 0, 0, 0);
      int hid0 = m * 16 + g * 4;
      f32x4v b1v = *(const f32x4v*)(b1 + hid0);
      half4v hv;
#pragma unroll
      for (int i = 0; i < 4; ++i) hv[i] = (_Float16)fmaxf(acc[i] + b1v[i], 0.f);
      *(half4v*)(&hscr[w][l15][hid0]) = hv;
    }
  }
  __syncthreads();

  // ---- Phase E: GEMM2  dx = W2 h + b2; epilogue U_s = M + dx*upd ----
  f32x4v acc2a = (f32x4v){0.f,0.f,0.f,0.f}, acc2b = (f32x4v){0.f,0.f,0.f,0.f};
#pragma unroll
  for (int kc = 0; kc < 4; ++kc) {
    half8 bf  = *(const half8*)(&hscr[w][l15][kc * 32 + g * 8]);
    half8 w2a = *(const half8*)(w2img + l15 * 128 + kc * 32 + g * 8);
    half8 w2b = *(const half8*)(w2img + (16 + l15) * 128 + kc * 32 + g * 8);
    acc2a = __builtin_amdgcn_mfma_f32_16x16x32_f16(w2a, bf, acc2a, 0, 0, 0);
    acc2b = __builtin_amdgcn_mfma_f32_16x16x32_f16(w2b, bf, acc2b, 0, 0, 0);
  }
  {
    int gY = y0 + w, gX = x0 + l15;
    int ip = gY * Wn + gX;
    float upd = (rplane[(size_t)b * HW + ip] < 0.5f) ? 1.f : 0.f;
    float* ob = outU + (size_t)b * Cn * HW;
    int my = w + 1, mx = l15 + 1;
    f32x4v b2v = *(const f32x4v*)(b2 + g * 4);
#pragma unroll
    for (int i = 0; i < 4; ++i) {
      int c = g * 4 + i;
      ob[c * HW + ip] = fmaf(acc2a[i] + b2v[i], upd, Mt[c][my][mx]);
    }
    if (g == 0)
      ob[16 * HW + ip] = fmaf(acc2b[0] + b2[16], upd, Mt[16][my][mx]);
  }
}

// finalize: M_47 = U_47 * alive(M_46.ch3, U_47.ch3); write dev_path[47] + final4
__global__ __launch_bounds__(256) void nca_finalize(
    const float* __restrict__ U, const float* __restrict__ Mprev,
    float* __restrict__ Mout, float* __restrict__ final4)
{
  int t = blockIdx.x * 256 + threadIdx.x;
  int x = t & 127, y = (t >> 7) & 127, b = t >> 14;
  const float* u3 = U + ((size_t)b * Cn + 3) * HW;
  const float* m3 = Mprev + ((size_t)b * Cn + 3) * HW;
  float pre = -1e30f, post = -1e30f;
#pragma unroll
  for (int dy = -1; dy <= 1; ++dy) {
    int yy = y + dy; if ((unsigned)yy >= 128u) continue;
#pragma unroll
    for (int dxx = -1; dxx <= 1; ++dxx) {
      int xx = x + dxx; if ((unsigned)xx >= 128u) continue;
      pre = fmaxf(pre, m3[yy * Wn + xx]);
      post = fmaxf(post, u3[yy * Wn + xx]);
    }
  }
  float alive = (pre > 0.1f && post > 0.1f) ? 1.f : 0.f;
  int ip = y * Wn + x;
#pragma unroll
  for (int c = 0; c < Cn; ++c) {
    float v = U[((size_t)b * Cn + c) * HW + ip] * alive;
    Mout[((size_t)b * Cn + c) * HW + ip] = v;
    if (c < 4) final4[((size_t)b * 4 + c) * HW + ip] = v;
  }
}

extern "C" void kernel_launch(void* const* d_in, const int* in_sizes, int n_in,
                              void* d_out, int out_size, void* d_ws, size_t ws_size,
                              hipStream_t stream) {
  const float* init_state = (const float*)d_in[0];
  const float* rand_all   = (const float*)d_in[1];
  const float* W1 = (const float*)d_in[2];
  const float* b1 = (const float*)d_in[3];
  const float* W2 = (const float*)d_in[4];
  const float* b2 = (const float*)d_in[5];

  float* out = (float*)d_out;
  float* final4 = out;                                 // [B,4,H,W]
  float* dev_path = out + (size_t)Bn * 4 * HW;         // [48][B][17][H][W]
  char* ws = (char*)d_ws;
  _Float16* w1img = (_Float16*)(ws + W1IMG_OFF);
  _Float16* w2img = (_Float16*)(ws + W2IMG_OFF);
  float* Ulast = (float*)(ws + ULAST_OFF);

  const size_t stateSz = (size_t)Bn * Cn * HW;
  auto slot = [&](int i) { return dev_path + (size_t)i * stateSz; };

  hipLaunchKernelGGL(nca_prep, dim3(52), dim3(256), 0, stream, W1, W2, w1img, w2img);

  // U_s parking: U_s -> slot(s+1) for s<=46; U_47 -> Ulast (ws).
  // step_s (s>=1) reads U_{s-1} from slot(s), writes M_{s-1} -> slot(s-1).
  hipLaunchKernelGGL((nca_step<0>), dim3(1024), dim3(256), 0, stream,
                     init_state, (const float*)nullptr, rand_all,
                     w1img, b1, w2img, b2, slot(1), (float*)nullptr);
  for (int s = 1; s < STEPSn; ++s) {
    const float* prevU = slot(s);
    const float* prev2 = (s >= 2) ? slot(s - 2) : init_state;
    float* outU = (s < STEPSn - 1) ? slot(s + 1) : Ulast;
    hipLaunchKernelGGL((nca_step<1>), dim3(1024), dim3(256), 0, stream,
                       prevU, prev2, rand_all + (size_t)s * NPIX,
                       w1img, b1, w2img, b2, outU, slot(s - 1));
  }
  hipLaunchKernelGGL(nca_finalize, dim3(NPIX / 256), dim3(256), 0, stream,
                     Ulast, slot(STEPSn - 2), slot(STEPSn - 1), final4);
}